// Round 15
// baseline (230.760 us; speedup 1.0000x reference)
//
#include <hip/hip_runtime.h>
#include <math.h>

#define EPS 1e-5f

constexpr int Bv   = 16384;   // batch
constexpr int Dv   = 1024;    // hidden
constexpr int Lv   = 3;       // blocks
constexpr int NKVv = 128;
constexpr int Vv   = 256;
constexpr int OUTv = 256;
constexpr int ZLD  = Lv * Dv; // 3072 concat width (bf16 buffer row stride)

typedef short bf16x8 __attribute__((ext_vector_type(8)));
typedef float f32x4  __attribute__((ext_vector_type(4)));

using gas_t = __attribute__((address_space(1))) const void;
using las_t = __attribute__((address_space(3))) void;
#define GLD_LDS16(gp, lp) \
    __builtin_amdgcn_global_load_lds((gas_t*)(gp), (las_t*)(lp), 16, 0, 0)

// round-to-nearest-even f32 -> bf16 bits
static __device__ __forceinline__ ushort f2bf(float f) {
    unsigned u = __float_as_uint(f);
    u = (u + 0x7fffu + ((u >> 16) & 1u)) >> 16;
    return (ushort)u;
}
// f32 <-> f16 (RTNE via hardware cvt)
static __device__ __forceinline__ ushort f2h(float f) {
    return __builtin_bit_cast(ushort, (_Float16)f);
}
static __device__ __forceinline__ float h2f(ushort u) {
    return (float)__builtin_bit_cast(_Float16, u);
}

// ---------------------------------------------------------------------------
// prep: vmean_i[v] = mean_n values[i][n][v]; cvec[r] = <vmean tile, Wout row r>
// (softmax rows sum to exactly 1 -> attention == add constant vector)
// ---------------------------------------------------------------------------
__global__ void vmean_kernel(const float* __restrict__ values,
                             float* __restrict__ vmean) {
    const int i = blockIdx.x, t = threadIdx.x;
    const float* vals = values + (size_t)i * NKVv * Vv;
    float s = 0.f;
    for (int n = 0; n < NKVv; ++n) s += vals[n * Vv + t];
    vmean[i * Vv + t] = s * (1.0f / NKVv);
}

__global__ void cvec_kernel(const float* __restrict__ vmean,
                            const float* __restrict__ Wout,
                            float* __restrict__ cvec) {
    const int w = threadIdx.x >> 6, lane = threadIdx.x & 63;
    const int r = blockIdx.x * 8 + w;          // 0..L*1024-1
    const int i = r >> 10;
    const float4 mv = *(const float4*)&vmean[i * Vv + lane * 4];
    const float* row = Wout + (size_t)r * 1024;
    float acc = 0.f;
#pragma unroll
    for (int c = 0; c < 4; ++c) {
        const float4 rv = *(const float4*)&row[c * 256 + lane * 4];
        acc += mv.x * rv.x + mv.y * rv.y + mv.z * rv.z + mv.w * rv.w;
    }
#pragma unroll
    for (int o = 1; o < 64; o <<= 1) acc += __shfl_xor(acc, o, 64);
    if (lane == 0) cvec[r] = acc;
}

// ---------------------------------------------------------------------------
// wprep: one block per W row (i,n). Single read of W does BOTH:
//   Wb[i][n][k] = bf16(W[i][n][k] * g_{i-1}[k])  (layer 0 unscaled)
//   ub/vb[i-1][n] = <g_{i-1} | lnb_{i-1}, W[i][n,:]>  (layers 1,2 only)
// ---------------------------------------------------------------------------
__global__ void wprep(const float* __restrict__ W,
                      const float* __restrict__ lng,
                      const float* __restrict__ lnb,
                      ushort* __restrict__ Wb,
                      float* __restrict__ ub, float* __restrict__ vb) {
    __shared__ float rs[8];
    const int row = blockIdx.x;          // 0..3071
    const int i = row >> 10, n = row & 1023;
    const int t = threadIdx.x, lane = t & 63, wv = t >> 6;
    const float* Wr = W + (size_t)row * 1024;
    const float4 w4 = *(const float4*)&Wr[t * 4];
    float4 g4 = make_float4(1.f, 1.f, 1.f, 1.f);
    float4 b4 = make_float4(0.f, 0.f, 0.f, 0.f);
    if (i > 0) {
        g4 = *(const float4*)&lng[(i - 1) * 1024 + t * 4];
        b4 = *(const float4*)&lnb[(i - 1) * 1024 + t * 4];
    }
    const float s0 = w4.x * g4.x, s1 = w4.y * g4.y, s2 = w4.z * g4.z, s3 = w4.w * g4.w;
    ushort4 o = {f2bf(s0), f2bf(s1), f2bf(s2), f2bf(s3)};
    *(ushort4*)&Wb[(size_t)row * 1024 + t * 4] = o;
    float su = s0 + s1 + s2 + s3;
    float sv = w4.x * b4.x + w4.y * b4.y + w4.z * b4.z + w4.w * b4.w;
#pragma unroll
    for (int d = 1; d < 64; d <<= 1) {
        su += __shfl_xor(su, d, 64);
        sv += __shfl_xor(sv, d, 64);
    }
    if (lane == 0) { rs[wv * 2] = su; rs[wv * 2 + 1] = sv; }
    __syncthreads();
    if (t == 0 && i > 0) {
        ub[(i - 1) * 1024 + n] = rs[0] + rs[2] + rs[4] + rs[6];
        vb[(i - 1) * 1024 + n] = rs[1] + rs[3] + rs[5] + rs[7];
    }
}

// wfprep: one block per (slice i, out-row n). Single Wf read does:
//   Wfb[n][i*1024+k] = bf16(Wf[n][i*1024+k] * g_i[k])
//   uf/vf[i][n] = <g_i | lnb_i, Wf[n, i-slice]>
__global__ void wfprep(const float* __restrict__ Wf,
                       const float* __restrict__ lng,
                       const float* __restrict__ lnb,
                       ushort* __restrict__ Wfb,
                       float* __restrict__ uf, float* __restrict__ vf) {
    __shared__ float rs[8];
    const int bid = blockIdx.x;          // 0..767 = i*256 + n
    const int i = bid >> 8, n = bid & 255;
    const int t = threadIdx.x, lane = t & 63, wv = t >> 6;
    const size_t base = (size_t)n * ZLD + i * 1024 + t * 4;
    const float4 w4 = *(const float4*)&Wf[base];
    const float4 g4 = *(const float4*)&lng[i * 1024 + t * 4];
    const float4 b4 = *(const float4*)&lnb[i * 1024 + t * 4];
    const float s0 = w4.x * g4.x, s1 = w4.y * g4.y, s2 = w4.z * g4.z, s3 = w4.w * g4.w;
    ushort4 o = {f2bf(s0), f2bf(s1), f2bf(s2), f2bf(s3)};
    *(ushort4*)&Wfb[base] = o;
    float su = s0 + s1 + s2 + s3;
    float sv = w4.x * b4.x + w4.y * b4.y + w4.z * b4.z + w4.w * b4.w;
#pragma unroll
    for (int d = 1; d < 64; d <<= 1) {
        su += __shfl_xor(su, d, 64);
        sv += __shfl_xor(sv, d, 64);
    }
    if (lane == 0) { rs[wv * 2] = su; rs[wv * 2 + 1] = sv; }
    __syncthreads();
    if (t == 0) {
        uf[i * 256 + n] = rs[0] + rs[2] + rs[4] + rs[6];
        vf[i * 256 + n] = rs[1] + rs[3] + rs[5] + rs[7];
    }
}

// x (B,1024) f32 -> bf16 into zbuf[:, 2048:3072] (row stride ZLD)
__global__ void conv_x(const float* __restrict__ x, ushort* __restrict__ z) {
    const int t = blockIdx.x * 256 + threadIdx.x;  // B*128 threads
    const int row = t >> 7, c8 = (t & 127) << 3;
    const float4 v0 = *(const float4*)&x[(size_t)row * 1024 + c8];
    const float4 v1 = *(const float4*)&x[(size_t)row * 1024 + c8 + 4];
    ushort4 o0 = {f2bf(v0.x), f2bf(v0.y), f2bf(v0.z), f2bf(v0.w)};
    ushort4 o1 = {f2bf(v1.x), f2bf(v1.y), f2bf(v1.z), f2bf(v1.w)};
    ushort* p = z + (size_t)row * ZLD + 2048 + c8;
    *(ushort4*)p       = o0;
    *(ushort4*)(p + 4) = o1;
}

// ---------------------------------------------------------------------------
// 128x128 bf16 MFMA NT GEMM — multi-block-per-CU variant (m97 geometry +
// all accumulated fusions). 4 waves (2Mx2N, per-wave 64x64), BK=32, 2-buf
// LDS (32 KB staging, 35 KB total) -> 4 blocks/CU co-resident
// (__launch_bounds__(256,4) caps VGPR at 128). Counted-vmcnt pipeline:
//   iter t: barrier#1 (tile t-1 reads retired collectively);
//           STAGE(t+1 -> buf t+1&1); vmcnt(4) binds stage(t); barrier#2;
//           8 ds_read_b128 + 16 MFMA.  Tail: vmcnt(0).
// Bank swizzle (4 chunks/row): phys = logical ^ ((row>>1)&3) -> 2-way max
// (free). Linear LDS dest; inverse-swizzled global source; swizzled read.
// Fused (m,r) prologue (pre-stage, rule-18 sched_barrier) in slab [34816,
// 35840). Epilogue: fused LN pass 1 + LDS-transpose coalesced store.
//
// MODE 0 (layer 0): val = relu(acc+bias)+cvec -> pstats + bf16 store.
// MODE 2 (layers 1,2): val = relu(r*acc - r*m*u + v + bias) + cvec;
//   bx==0 publishes mr3. MODE 1 (final, split-K): raw acc -> f16 psum;
//   slice==2 & bxn==0 computes+publishes mr3(layer2).
// Grid: 1024 blocks (MODE 0/2: 128 by x 8 bx) or 768 (MODE 1: 3 x 128 x 2).
// ---------------------------------------------------------------------------
#define STAGE128(KT, BI)                                                      \
    do {                                                                      \
        GLD_LDS16(gAs + (size_t)(w16)      * lda + (KT) * 32,                 \
                  As + (BI) * 4096 + (w16) * 32);                             \
        GLD_LDS16(gAs + (size_t)(w16 + 64) * lda + (KT) * 32,                 \
                  As + (BI) * 4096 + (w16 + 64) * 32);                        \
        GLD_LDS16(gBs + (size_t)(w16)      * ldb + (KT) * 32,                 \
                  Bs + (BI) * 4096 + (w16) * 32);                             \
        GLD_LDS16(gBs + (size_t)(w16 + 64) * ldb + (KT) * 32,                 \
                  Bs + (BI) * 4096 + (w16 + 64) * 32);                        \
    } while (0)

template<int MODE>
__global__ __launch_bounds__(256, 4)
void gemm128(const ushort* __restrict__ A, int lda,
             const ushort* __restrict__ Bw, int ldb,
             const float* __restrict__ bias,
             const float* __restrict__ cvec,
             const float* __restrict__ u_,
             const float* __restrict__ v_,
             const float2* __restrict__ pstats_in,   // prev-layer stats (B,16)
             float2* __restrict__ mrout,             // global (B) mr publish
             void* __restrict__ Cv, int ldc,
             int NT,
             float2* __restrict__ pstats_out) {
    // [0,16384) As[2][128][32] | [16384,32768) Bs[2][128][32] |
    // epilogue tile [128][136] over [0,34816) | mrs slab [34816,35840)
    __shared__ __align__(16) char smem[35840];
    ushort* As = (ushort*)smem;
    ushort* Bs = (ushort*)(smem + 16384);
    float2* mrs = (float2*)(smem + 34816);
    const int tid  = threadIdx.x;
    const int lane = tid & 63;
    const int w    = tid >> 6;        // wave 0..3
    const int wr   = w >> 1, wc = w & 1;
    const int w16  = w * 16;

    // block decomposition
    const int wg = blockIdx.x;
    int by, bx, koff;
    if (MODE == 1) {
        const int s = wg >> 8, r = wg & 255;    // slice 0..2
        by = r & 127; bx = r >> 7;              // bx = n-tile (0/1)
        koff = s * 1024;
    } else {
        const int j = wg >> 3;                  // XCD owns 16 by x 8 bx
        by = (wg & 7) * 16 + (j & 15);
        bx = j >> 4;
        koff = 0;
    }
    const int m0 = by * 128;
    const int n0 = bx * 128;
    const int slice = (MODE == 1) ? (wg >> 8) : 0;

    // staging source (inverse-swizzled chunk; LDS dest linear):
    // LDS(row, phys p) holds global(row, p ^ ((row>>1)&3)); row = lane>>2.
    const int schunk = ((lane & 3) ^ ((lane >> 3) & 3)) << 3;
    const ushort* gAs = A  + (size_t)(m0 + (lane >> 2)) * lda + koff + schunk;
    const ushort* gBs = Bw + (size_t)(n0 + (lane >> 2)) * ldb + koff + schunk;

    // fragment read addressing: logical chunk lane>>4, row wr*64+mf*16+frow
    const int frow = lane & 15;
    const int ck    = (((lane >> 4) ^ ((frow >> 1) & 3))) << 3;
    const int abase = (wr * 64 + frow) * 32 + ck;   // + mf*512 + buf*4096
    const int bbase = (wc * 64 + frow) * 32 + ck;   // + nf*512 + buf*4096

    f32x4 acc[4][4] = {};
    bf16x8 aR[4], bR[4];

    // ---- fused mr: load pstats rows, compute (mean, rsqrt), park in mrs.
    const bool doMR = (MODE == 2) || (MODE == 1 && slice == 2);
    float2 myMR = make_float2(0.f, 0.f);
    if (doMR && tid < 128) {
        const float4* pp = (const float4*)(pstats_in + (((size_t)(m0 + tid)) << 4));
        float sum = 0.f, sq = 0.f;
#pragma unroll
        for (int j = 0; j < 8; ++j) {
            const float4 t4 = pp[j];
            sum += t4.x + t4.z; sq += t4.y + t4.w;
        }
        const float m = sum * (1.f / Dv);
        const float var = sq * (1.f / Dv) - m * m;
        myMR = make_float2(m, rsqrtf(var + EPS));
        if (MODE == 2) mrs[tid] = myMR;
    }
    __builtin_amdgcn_sched_barrier(0);   // pstats loads fully retired first

    // prologue: stage tile 0 into buf 0
    STAGE128(0, 0);

    for (int t = 0; t < NT; ++t) {
        const int d = t & 1;
        const bool pf = (t + 1) < NT;
        __builtin_amdgcn_s_barrier();          // #1: tile t-1 reads retired
        if (pf) STAGE128(t + 1, d ^ 1);        // overwrites tile t-1's buf
        if (pf) asm volatile("s_waitcnt vmcnt(4)" ::: "memory");  // binds stage(t)
        else    asm volatile("s_waitcnt vmcnt(0)" ::: "memory");
        __builtin_amdgcn_s_barrier();          // #2: tile t resident
        const ushort* Ab = As + d * 4096;
        const ushort* Bb = Bs + d * 4096;
#pragma unroll
        for (int mf = 0; mf < 4; ++mf) aR[mf] = *(const bf16x8*)&Ab[abase + mf * 512];
#pragma unroll
        for (int nf = 0; nf < 4; ++nf) bR[nf] = *(const bf16x8*)&Bb[bbase + nf * 512];
        __builtin_amdgcn_s_setprio(1);
#pragma unroll
        for (int mf = 0; mf < 4; ++mf)
#pragma unroll
            for (int nf = 0; nf < 4; ++nf)
                acc[mf][nf] = __builtin_amdgcn_mfma_f32_16x16x32_bf16(
                    aR[mf], bR[nf], acc[mf][nf], 0, 0, 0);
        __builtin_amdgcn_s_setprio(0);
    }

    // publish mr3 (global store safe now — vmcnt games over)
    if (doMR && tid < 128 && bx == 0) mrout[m0 + tid] = myMR;

    // epilogue: C/D layout col = lane&15, row = (lane>>4)*4 + r  [m89-verified]
    const int lg4 = (lane >> 4) << 2;
    ushort* tile = (ushort*)smem;   // [128][136], 272B rows
    if (MODE != 1) {
        float bsv[4], csv[4], uu[4], vv[4];
#pragma unroll
        for (int nf = 0; nf < 4; ++nf) {
            const int col = n0 + wc * 64 + nf * 16 + (lane & 15);
            bsv[nf] = bias[col];
            csv[nf] = cvec[col];
            if (MODE == 2) { uu[nf] = u_[col]; vv[nf] = v_[col]; }
        }
        __syncthreads();                       // staging LDS dead in all waves
        // fused epilogue + LN pass 1 (row partials over this wave's 64 cols)
#pragma unroll
        for (int mf = 0; mf < 4; ++mf)
#pragma unroll
            for (int r = 0; r < 4; ++r) {
                const int rloc = wr * 64 + mf * 16 + lg4 + r;
                float rw = 1.f, rmw = 0.f;
                if (MODE == 2) {
                    const float2 q = mrs[rloc];
                    rw = q.y; rmw = q.y * q.x;
                }
                float sum = 0.f, sq = 0.f;
#pragma unroll
                for (int nf = 0; nf < 4; ++nf) {
                    float a = acc[mf][nf][r];
                    float val;
                    if (MODE == 2)
                        val = fmaf(rw, a, fmaf(-rmw, uu[nf], vv[nf] + bsv[nf]));
                    else
                        val = a + bsv[nf];
                    val = fmaxf(val, 0.f) + csv[nf];
                    acc[mf][nf][r] = val;
                    sum += val; sq += val * val;
                }
#pragma unroll
                for (int o = 1; o < 16; o <<= 1) {
                    sum += __shfl_xor(sum, o, 64);
                    sq  += __shfl_xor(sq,  o, 64);
                }
                if ((lane & 15) == 0)
                    pstats_out[(((size_t)(m0 + rloc)) << 4) + (bx << 1) + wc] =
                        make_float2(sum, sq);
            }
        // bf16 transpose tile + coalesced store into zbuf slot
#pragma unroll
        for (int mf = 0; mf < 4; ++mf)
#pragma unroll
            for (int nf = 0; nf < 4; ++nf)
#pragma unroll
                for (int r = 0; r < 4; ++r) {
                    const int rloc = wr * 64 + mf * 16 + lg4 + r;
                    const int cloc = wc * 64 + nf * 16 + (lane & 15);
                    tile[rloc * 136 + cloc] = f2bf(acc[mf][nf][r]);
                }
    } else {
        // MODE 1: raw f32 acc -> f16 tile (coalesced store below)
        __syncthreads();
#pragma unroll
        for (int mf = 0; mf < 4; ++mf)
#pragma unroll
            for (int nf = 0; nf < 4; ++nf)
#pragma unroll
                for (int r = 0; r < 4; ++r) {
                    const int rloc = wr * 64 + mf * 16 + lg4 + r;
                    const int cloc = wc * 64 + nf * 16 + (lane & 15);
                    tile[rloc * 136 + cloc] = f2h(acc[mf][nf][r]);
                }
    }
    __syncthreads();
    ushort* C16 = (MODE == 1)
        ? ((ushort*)Cv + (size_t)slice * ((size_t)Bv * OUTv))
        : (ushort*)Cv;
    for (int c = tid; c < 128 * 16; c += 256) {
        const int row = c >> 4, ch = (c & 15) << 3;
        const bf16x8 v = *(const bf16x8*)&tile[row * 136 + ch];
        *(bf16x8*)&C16[(size_t)(m0 + row) * ldc + n0 + ch] = v;
    }
}

// ---------------------------------------------------------------------------
// Final: per-layer LN-folded reduce + bias + LayerNorm(256) + sigmoid.
// val[n] = sum_i r_i*(ps_i[n] - m_i*uf_i[n]) + sum_i vf_i[n] + bf[n]
// psum slices are f16. 4 rows/block, 1 wave per row, 4 cols/lane.
// ---------------------------------------------------------------------------
__global__ void ln_sig_reduce(const ushort* __restrict__ ps,   // f16 (3,B,256)
                              const float2* __restrict__ mr,   // (3,B)
                              const float* __restrict__ uf,    // (3,256)
                              const float* __restrict__ vf,    // (3,256)
                              const float* __restrict__ bf_,
                              const float* __restrict__ g,
                              const float* __restrict__ bb,
                              float* __restrict__ y) {
    const int lane = threadIdx.x & 63;
    const int row  = blockIdx.x * 4 + (threadIdx.x >> 6);
    const size_t base = (size_t)row * OUTv + lane * 4;
    const size_t SP = (size_t)Bv * OUTv;
    const float2 q0 = mr[row];
    const float2 q1 = mr[Bv + row];
    const float2 q2 = mr[2 * Bv + row];
    const ushort4 a0 = *(const ushort4*)&ps[base];
    const ushort4 a1 = *(const ushort4*)&ps[base + SP];
    const ushort4 a2 = *(const ushort4*)&ps[base + 2 * SP];
    const float4 u0 = *(const float4*)&uf[lane * 4];
    const float4 u1 = *(const float4*)&uf[256 + lane * 4];
    const float4 u2 = *(const float4*)&uf[512 + lane * 4];
    const float4 f0 = *(const float4*)&vf[lane * 4];
    const float4 f1 = *(const float4*)&vf[256 + lane * 4];
    const float4 f2 = *(const float4*)&vf[512 + lane * 4];
    const float4 bv4 = *(const float4*)&bf_[lane * 4];
    const float cst_x = f0.x + f1.x + f2.x + bv4.x;
    const float cst_y = f0.y + f1.y + f2.y + bv4.y;
    const float cst_z = f0.z + f1.z + f2.z + bv4.z;
    const float cst_w = f0.w + f1.w + f2.w + bv4.w;
    const float v0 = q0.y * (h2f(a0.x) - q0.x * u0.x) + q1.y * (h2f(a1.x) - q1.x * u1.x)
                   + q2.y * (h2f(a2.x) - q2.x * u2.x) + cst_x;
    const float v1 = q0.y * (h2f(a0.y) - q0.x * u0.y) + q1.y * (h2f(a1.y) - q1.x * u1.y)
                   + q2.y * (h2f(a2.y) - q2.x * u2.y) + cst_y;
    const float v2 = q0.y * (h2f(a0.z) - q0.x * u0.z) + q1.y * (h2f(a1.z) - q1.x * u1.z)
                   + q2.y * (h2f(a2.z) - q2.x * u2.z) + cst_z;
    const float v3 = q0.y * (h2f(a0.w) - q0.x * u0.w) + q1.y * (h2f(a1.w) - q1.x * u1.w)
                   + q2.y * (h2f(a2.w) - q2.x * u2.w) + cst_w;
    float s = v0 + v1 + v2 + v3;
#pragma unroll
    for (int o = 1; o < 64; o <<= 1) s += __shfl_xor(s, o, 64);
    const float mean = s * (1.f / OUTv);
    const float d0 = v0 - mean, d1 = v1 - mean, d2 = v2 - mean, d3 = v3 - mean;
    float q = d0 * d0 + d1 * d1 + d2 * d2 + d3 * d3;
#pragma unroll
    for (int o = 1; o < 64; o <<= 1) q += __shfl_xor(q, o, 64);
    const float r = rsqrtf(q * (1.f / OUTv) + EPS);
    const float4 gg = *(const float4*)&g[lane * 4];
    const float4 bv = *(const float4*)&bb[lane * 4];
    float4 o;
    const float t0 = d0 * r * gg.x + bv.x;
    const float t1 = d1 * r * gg.y + bv.y;
    const float t2 = d2 * r * gg.z + bv.z;
    const float t3 = d3 * r * gg.w + bv.w;
    o.x = 1.f / (1.f + expf(-t0));
    o.y = 1.f / (1.f + expf(-t1));
    o.z = 1.f / (1.f + expf(-t2));
    o.w = 1.f / (1.f + expf(-t3));
    *(float4*)&y[base] = o;
}

// ---------------------------------------------------------------------------
extern "C" void kernel_launch(void* const* d_in, const int* in_sizes, int n_in,
                              void* d_out, int out_size, void* d_ws, size_t ws_size,
                              hipStream_t stream) {
    const float* x      = (const float*)d_in[0];
    const float* W      = (const float*)d_in[1];
    const float* b      = (const float*)d_in[2];
    // d_in[3] = Wq, d_in[4] = keys : dead code (softmax row-sums are 1)
    const float* values = (const float*)d_in[5];
    const float* Wout   = (const float*)d_in[6];
    const float* ln_g   = (const float*)d_in[7];
    const float* ln_b   = (const float*)d_in[8];
    const float* Wf     = (const float*)d_in[9];
    const float* bf     = (const float*)d_in[10];
    const float* lnf_g  = (const float*)d_in[11];
    const float* lnf_b  = (const float*)d_in[12];
    float* out = (float*)d_out;

    // workspace layout (~140 MB):
    char* ws = (char*)d_ws;
    ushort* zbuf = (ushort*)ws;                                  // (B,3072) bf16 RAW h + xb
    ws += (size_t)Bv * ZLD * sizeof(ushort);                     // 100.7 MB
    ushort* psum = (ushort*)ws;                                  // (3,B,256) f16 split-K partials
    ws += (size_t)3 * Bv * OUTv * sizeof(ushort);                // 25.2 MB
    ushort* Wb = (ushort*)ws;                                    // (L,1024,1024) bf16 g-folded
    ws += (size_t)Lv * Dv * Dv * sizeof(ushort);                 // 6.3 MB
    ushort* Wfb = (ushort*)ws;                                   // (256,3072) bf16 g-folded
    ws += (size_t)OUTv * ZLD * sizeof(ushort);                   // 1.6 MB
    float* cvec = (float*)ws;                                    // (L,1024)
    ws += (size_t)Lv * Dv * sizeof(float);
    float* vmean = (float*)ws;                                   // (L,256)
    ws += (size_t)Lv * Vv * sizeof(float);
    float2* psA = (float2*)ws;                                   // (B,16) ping
    ws += (size_t)Bv * 16 * sizeof(float2);                      // 2 MB
    float2* psB = (float2*)ws;                                   // (B,16) pong
    ws += (size_t)Bv * 16 * sizeof(float2);                      // 2 MB
    float2* mr3 = (float2*)ws;                                   // (3,B)
    ws += (size_t)3 * Bv * sizeof(float2);                       // 384 KB
    float* ub = (float*)ws; ws += 2 * Dv * sizeof(float);        // (2,1024)
    float* vb = (float*)ws; ws += 2 * Dv * sizeof(float);
    float* uf = (float*)ws; ws += 3 * OUTv * sizeof(float);      // (3,256)
    float* vf = (float*)ws; ws += 3 * OUTv * sizeof(float);

    // prep (single-read fused weight converts + fold vectors)
    wprep<<<Lv * Dv, 256, 0, stream>>>(W, ln_g, ln_b, Wb, ub, vb);
    wfprep<<<3 * OUTv, 256, 0, stream>>>(Wf, ln_g, ln_b, Wfb, uf, vf);
    conv_x<<<Bv * 128 / 256, 256, 0, stream>>>(x, zbuf);
    vmean_kernel<<<Lv, 256, 0, stream>>>(values, vmean);
    cvec_kernel<<<Lv * Dv / 8, 512, 0, stream>>>(vmean, Wout, cvec);

    // layer 0: A = xb (cols 2048:3072) -> raw h0 + pstats into psA
    gemm128<0><<<dim3(1024), 256, 0, stream>>>(
        zbuf + 2048, ZLD, Wb, Dv,
        b, cvec, nullptr, nullptr, nullptr, nullptr,
        (void*)(zbuf + 0), ZLD, /*NT=*/32, psA);

    // layer 1: fused mr(layer0) from psA; writes pstats(layer1) -> psB
    gemm128<2><<<dim3(1024), 256, 0, stream>>>(
        zbuf, ZLD, Wb + (size_t)Dv * Dv, Dv,
        b + Dv, cvec + Dv, ub, vb, psA, mr3,
        (void*)(zbuf + Dv), ZLD, /*NT=*/32, psB);

    // layer 2: fused mr(layer1) from psB; writes pstats(layer2) -> psA
    gemm128<2><<<dim3(1024), 256, 0, stream>>>(
        zbuf + Dv, ZLD, Wb + (size_t)2 * Dv * Dv, Dv,
        b + 2 * Dv, cvec + 2 * Dv, ub + Dv, vb + Dv, psB, mr3 + Bv,
        (void*)(zbuf + 2 * Dv), ZLD, /*NT=*/32, psA);

    // final GEMM: split-K by layer (3 x K=1024), 768 blocks, f16 partials;
    // slice==2 blocks also compute+publish mr3(layer2) from psA.
    gemm128<1><<<dim3(768), 256, 0, stream>>>(
        zbuf, ZLD, Wfb, ZLD, nullptr, nullptr, nullptr, nullptr,
        psA, mr3 + 2 * Bv,
        (void*)psum, OUTv, /*NT=*/32, nullptr);

    ln_sig_reduce<<<Bv / 4, 256, 0, stream>>>(psum, mr3, uf, vf, bf,
                                              lnf_g, lnf_b, out);
}

// Round 16
// 195.071 us; speedup vs baseline: 1.1830x; 1.1830x over previous
//
#include <hip/hip_runtime.h>
#include <math.h>

#define EPS 1e-5f

constexpr int Bv   = 16384;   // batch
constexpr int Dv   = 1024;    // hidden
constexpr int Lv   = 3;       // blocks
constexpr int NKVv = 128;
constexpr int Vv   = 256;
constexpr int OUTv = 256;
constexpr int ZLD  = Lv * Dv; // 3072 concat width (bf16 buffer row stride)

typedef short bf16x8 __attribute__((ext_vector_type(8)));
typedef float f32x4  __attribute__((ext_vector_type(4)));

using gas_t = __attribute__((address_space(1))) const void;
using las_t = __attribute__((address_space(3))) void;
#define GLD_LDS16(gp, lp) \
    __builtin_amdgcn_global_load_lds((gas_t*)(gp), (las_t*)(lp), 16, 0, 0)

// round-to-nearest-even f32 -> bf16 bits
static __device__ __forceinline__ ushort f2bf(float f) {
    unsigned u = __float_as_uint(f);
    u = (u + 0x7fffu + ((u >> 16) & 1u)) >> 16;
    return (ushort)u;
}
// f32 <-> f16 (RTNE via hardware cvt)
static __device__ __forceinline__ ushort f2h(float f) {
    return __builtin_bit_cast(ushort, (_Float16)f);
}
static __device__ __forceinline__ float h2f(ushort u) {
    return (float)__builtin_bit_cast(_Float16, u);
}

// ---------------------------------------------------------------------------
// prep: vmean_i[v] = mean_n values[i][n][v]; cvec[r] = <vmean tile, Wout row r>
// (softmax rows sum to exactly 1 -> attention == add constant vector)
// ---------------------------------------------------------------------------
__global__ void vmean_kernel(const float* __restrict__ values,
                             float* __restrict__ vmean) {
    const int i = blockIdx.x, t = threadIdx.x;
    const float* vals = values + (size_t)i * NKVv * Vv;
    float s = 0.f;
    for (int n = 0; n < NKVv; ++n) s += vals[n * Vv + t];
    vmean[i * Vv + t] = s * (1.0f / NKVv);
}

__global__ void cvec_kernel(const float* __restrict__ vmean,
                            const float* __restrict__ Wout,
                            float* __restrict__ cvec) {
    const int w = threadIdx.x >> 6, lane = threadIdx.x & 63;
    const int r = blockIdx.x * 8 + w;          // 0..L*1024-1
    const int i = r >> 10;
    const float4 mv = *(const float4*)&vmean[i * Vv + lane * 4];
    const float* row = Wout + (size_t)r * 1024;
    float acc = 0.f;
#pragma unroll
    for (int c = 0; c < 4; ++c) {
        const float4 rv = *(const float4*)&row[c * 256 + lane * 4];
        acc += mv.x * rv.x + mv.y * rv.y + mv.z * rv.z + mv.w * rv.w;
    }
#pragma unroll
    for (int o = 1; o < 64; o <<= 1) acc += __shfl_xor(acc, o, 64);
    if (lane == 0) cvec[r] = acc;
}

// ---------------------------------------------------------------------------
// wprep: one block per W row (i,n). Single read of W does BOTH:
//   Wb[i][n][k] = bf16(W[i][n][k] * g_{i-1}[k])  (layer 0 unscaled)
//   ub/vb[i-1][n] = <g_{i-1} | lnb_{i-1}, W[i][n,:]>  (layers 1,2 only)
// ---------------------------------------------------------------------------
__global__ void wprep(const float* __restrict__ W,
                      const float* __restrict__ lng,
                      const float* __restrict__ lnb,
                      ushort* __restrict__ Wb,
                      float* __restrict__ ub, float* __restrict__ vb) {
    __shared__ float rs[8];
    const int row = blockIdx.x;          // 0..3071
    const int i = row >> 10, n = row & 1023;
    const int t = threadIdx.x, lane = t & 63, wv = t >> 6;
    const float* Wr = W + (size_t)row * 1024;
    const float4 w4 = *(const float4*)&Wr[t * 4];
    float4 g4 = make_float4(1.f, 1.f, 1.f, 1.f);
    float4 b4 = make_float4(0.f, 0.f, 0.f, 0.f);
    if (i > 0) {
        g4 = *(const float4*)&lng[(i - 1) * 1024 + t * 4];
        b4 = *(const float4*)&lnb[(i - 1) * 1024 + t * 4];
    }
    const float s0 = w4.x * g4.x, s1 = w4.y * g4.y, s2 = w4.z * g4.z, s3 = w4.w * g4.w;
    ushort4 o = {f2bf(s0), f2bf(s1), f2bf(s2), f2bf(s3)};
    *(ushort4*)&Wb[(size_t)row * 1024 + t * 4] = o;
    float su = s0 + s1 + s2 + s3;
    float sv = w4.x * b4.x + w4.y * b4.y + w4.z * b4.z + w4.w * b4.w;
#pragma unroll
    for (int d = 1; d < 64; d <<= 1) {
        su += __shfl_xor(su, d, 64);
        sv += __shfl_xor(sv, d, 64);
    }
    if (lane == 0) { rs[wv * 2] = su; rs[wv * 2 + 1] = sv; }
    __syncthreads();
    if (t == 0 && i > 0) {
        ub[(i - 1) * 1024 + n] = rs[0] + rs[2] + rs[4] + rs[6];
        vb[(i - 1) * 1024 + n] = rs[1] + rs[3] + rs[5] + rs[7];
    }
}

// wfprep: one block per (slice i, out-row n). Single Wf read does:
//   Wfb[n][i*1024+k] = bf16(Wf[n][i*1024+k] * g_i[k])
//   uf/vf[i][n] = <g_i | lnb_i, Wf[n, i-slice]>
__global__ void wfprep(const float* __restrict__ Wf,
                       const float* __restrict__ lng,
                       const float* __restrict__ lnb,
                       ushort* __restrict__ Wfb,
                       float* __restrict__ uf, float* __restrict__ vf) {
    __shared__ float rs[8];
    const int bid = blockIdx.x;          // 0..767 = i*256 + n
    const int i = bid >> 8, n = bid & 255;
    const int t = threadIdx.x, lane = t & 63, wv = t >> 6;
    const size_t base = (size_t)n * ZLD + i * 1024 + t * 4;
    const float4 w4 = *(const float4*)&Wf[base];
    const float4 g4 = *(const float4*)&lng[i * 1024 + t * 4];
    const float4 b4 = *(const float4*)&lnb[i * 1024 + t * 4];
    const float s0 = w4.x * g4.x, s1 = w4.y * g4.y, s2 = w4.z * g4.z, s3 = w4.w * g4.w;
    ushort4 o = {f2bf(s0), f2bf(s1), f2bf(s2), f2bf(s3)};
    *(ushort4*)&Wfb[base] = o;
    float su = s0 + s1 + s2 + s3;
    float sv = w4.x * b4.x + w4.y * b4.y + w4.z * b4.z + w4.w * b4.w;
#pragma unroll
    for (int d = 1; d < 64; d <<= 1) {
        su += __shfl_xor(su, d, 64);
        sv += __shfl_xor(sv, d, 64);
    }
    if (lane == 0) { rs[wv * 2] = su; rs[wv * 2 + 1] = sv; }
    __syncthreads();
    if (t == 0) {
        uf[i * 256 + n] = rs[0] + rs[2] + rs[4] + rs[6];
        vf[i * 256 + n] = rs[1] + rs[3] + rs[5] + rs[7];
    }
}

// x (B,1024) f32 -> bf16 into zbuf[:, 2048:3072] (row stride ZLD)
__global__ void conv_x(const float* __restrict__ x, ushort* __restrict__ z) {
    const int t = blockIdx.x * 256 + threadIdx.x;  // B*128 threads
    const int row = t >> 7, c8 = (t & 127) << 3;
    const float4 v0 = *(const float4*)&x[(size_t)row * 1024 + c8];
    const float4 v1 = *(const float4*)&x[(size_t)row * 1024 + c8 + 4];
    ushort4 o0 = {f2bf(v0.x), f2bf(v0.y), f2bf(v0.z), f2bf(v0.w)};
    ushort4 o1 = {f2bf(v1.x), f2bf(v1.y), f2bf(v1.z), f2bf(v1.w)};
    ushort* p = z + (size_t)row * ZLD + 2048 + c8;
    *(ushort4*)p       = o0;
    *(ushort4*)(p + 4) = o1;
}

// ---------------------------------------------------------------------------
// 256x256 bf16 MFMA NT GEMM — round-10 K-loop (read-early, 3 counted-vmcnt
// barriers per tile — measured best) + round-11 L2 block mapping (each XCD
// owns 8 by x 4 bx: A working set 4MB + B 2MB fit its private L2; FETCH
// measured 2.8x lower). XOR bank-swizzle: linear LDS dest, inverse-swizzled
// global source, swizzled ds_read. Fused (m,r) in prologue (drained
// pre-stage, rule-18 sched_barrier) parked in LDS slab [137216,139264).
//
// MODE 0 (layer 0): val = relu(acc+bias)+cvec; row (sum,sq) -> pstats_out;
//   bf16 stored coalesced (LDS transpose) into zbuf slot (raw pre-LN h).
// MODE 2 (layers 1,2): prologue computes (m,r) of PREVIOUS layer from
//   pstats_in; epilogue val = relu(r*acc - r*m*u + v + bias) + cvec;
//   bx==0 blocks publish mr3. pstats ping-pongs between layers.
// MODE 1 (final, split-K by layer): raw acc -> f16 psum slice (coalesced);
//   bx==2 blocks compute+publish mr3 for layer 2.
// Grid: 256 blocks (MODE 0/2) or 192 blocks (MODE 1), 512 threads.
// ---------------------------------------------------------------------------
#define READ_A(QR, DD)                                                        \
    do { _Pragma("unroll")                                                    \
        for (int mf = 0; mf < 4; ++mf) {                                      \
            const int _o = (DD) * 16384 + (QR) * 8192 + (arow_l + mf * 16) * 64; \
            aR[mf][0] = *(const bf16x8*)&As[_o + ck0];                        \
            aR[mf][1] = *(const bf16x8*)&As[_o + ck1];                        \
        } } while (0)

#define READ_B(QC, DD, BR)                                                    \
    do { _Pragma("unroll")                                                    \
        for (int nf = 0; nf < 2; ++nf) {                                      \
            const int _o = (DD) * 16384 + (QC) * 8192 + (brow_l + nf * 16) * 64; \
            BR[nf][0] = *(const bf16x8*)&Bs[_o + ck0];                        \
            BR[nf][1] = *(const bf16x8*)&Bs[_o + ck1];                        \
        } } while (0)

#define STAGE_A(KT, H, DD)                                                    \
    do { const ushort* _p = gAs + (size_t)((H) * 128 + w16) * lda + (KT) * 64; \
         ushort* _l = As + (DD) * 16384 + (H) * 8192 + w16 * 64;              \
         GLD_LDS16(_p, _l);                                                   \
         GLD_LDS16(_p + (size_t)8 * lda, _l + 512); } while (0)

#define STAGE_B(KT, H, DD)                                                    \
    do { const ushort* _p = gBs + (size_t)((H) * 128 + w16) * ldb + (KT) * 64; \
         ushort* _l = Bs + (DD) * 16384 + (H) * 8192 + w16 * 64;              \
         GLD_LDS16(_p, _l);                                                   \
         GLD_LDS16(_p + (size_t)8 * ldb, _l + 512); } while (0)

#define MFMA_Q(QR, QC, BR)                                                    \
    do { __builtin_amdgcn_s_setprio(1);                                       \
        _Pragma("unroll")                                                     \
        for (int mf = 0; mf < 4; ++mf) {                                      \
            _Pragma("unroll")                                                 \
            for (int nf = 0; nf < 2; ++nf) {                                  \
                acc[QR][QC][mf][nf] = __builtin_amdgcn_mfma_f32_16x16x32_bf16( \
                    aR[mf][0], BR[nf][0], acc[QR][QC][mf][nf], 0, 0, 0);      \
                acc[QR][QC][mf][nf] = __builtin_amdgcn_mfma_f32_16x16x32_bf16( \
                    aR[mf][1], BR[nf][1], acc[QR][QC][mf][nf], 0, 0, 0);      \
            }                                                                 \
        }                                                                     \
        __builtin_amdgcn_s_setprio(0); } while (0)

template<int MODE>
__global__ __launch_bounds__(512, 1)
void gemm256(const ushort* __restrict__ A, int lda,
             const ushort* __restrict__ Bw, int ldb,
             const float* __restrict__ bias,
             const float* __restrict__ cvec,
             const float* __restrict__ u_,
             const float* __restrict__ v_,
             const float2* __restrict__ pstats_in,   // prev-layer stats
             float2* __restrict__ mrout,             // global (B) mr publish
             void* __restrict__ Cv, int ldc,
             int NT, int ksplit,
             float2* __restrict__ pstats_out) {
    // [0,64K) As dbuf | [64K,128K) Bs dbuf | tile at +2048 (epilogue, over
    // As/Bs) | [137216,139264) mrs slab (persists through main loop)
    __shared__ __align__(16) char smem[139264];
    ushort* As = (ushort*)smem;            // [2][2][128][64]
    ushort* Bs = (ushort*)(smem + 65536);  // [2][2][128][64]
    float2* mrs = (float2*)(smem + 137216);
    const int tid  = threadIdx.x;
    const int lane = tid & 63;
    const int w    = tid >> 6;        // wave 0..7
    const int wr2  = w >> 2, wc2 = w & 3;
    const int w16  = w * 16;

    // block swizzle
    const int wg  = blockIdx.x;
    int by, bx;
    if (MODE == 1) {
        const int swz = (wg & 7) * 24 + (wg >> 3);   // 192 blocks, bx = k-slice
        by = swz & 63; bx = swz >> 6;
    } else {
        const int j = wg >> 3;                       // XCD gets 8 by x 4 bx
        by = (wg & 7) * 8 + (j & 7);
        bx = j >> 3;
    }
    const int m0  = by * 256;
    const int n0  = (MODE == 1) ? 0 : bx * 256;
    const int koff = (MODE == 1) ? bx * ksplit : 0;

    // staging source (inverse-XOR-swizzled column chunk; LDS dest is linear)
    const int swzc = ((lane & 7) ^ ((lane >> 3) & 7)) << 3;
    const ushort* gAs = A  + (size_t)(m0 + (lane >> 3)) * lda + koff + swzc;
    const ushort* gBs = Bw + (size_t)(n0 + (lane >> 3)) * ldb + koff + swzc;

    const int arow_l = wr2 * 64 + (lane & 15);
    const int brow_l = wc2 * 32 + (lane & 15);
    const int ck0 = (((lane >> 4))     ^ (lane & 7)) << 3;   // ks=0 chunk
    const int ck1 = ((4 + (lane >> 4)) ^ (lane & 7)) << 3;   // ks=1 chunk

    f32x4 acc[2][2][4][2] = {};
    bf16x8 aR[4][2], bR0[2][2], bR1[2][2];

    // ---- fused mr: load pstats rows, compute (mean, rsqrt), park in mrs.
    // Drained BEFORE stages issue (data-dep + sched_barrier) so the in-loop
    // vmcnt FIFO counts only stage loads.
    const bool doMR = (MODE == 2) || (MODE == 1 && bx == 2);
    float2 myMR = make_float2(0.f, 0.f);
    if (doMR && tid < 256) {
        const float4* pp = (const float4*)(pstats_in + (((size_t)(m0 + tid)) << 4));
        float sum = 0.f, sq = 0.f;
#pragma unroll
        for (int j = 0; j < 8; ++j) {
            const float4 t4 = pp[j];
            sum += t4.x + t4.z; sq += t4.y + t4.w;
        }
        const float m = sum * (1.f / Dv);
        const float var = sq * (1.f / Dv) - m * m;
        myMR = make_float2(m, rsqrtf(var + EPS));
        if (MODE == 2) mrs[tid] = myMR;
    }
    __builtin_amdgcn_sched_barrier(0);   // pstats loads fully retired first

    // prologue: tile 0 halves in steady-state stage order a0,b0,b1,a1;
    // vmcnt(4)+barrier binds A0(0),B0(0) == steady-state entry condition.
    STAGE_A(0, 0, 0);
    STAGE_B(0, 0, 0);
    STAGE_B(0, 1, 0);
    STAGE_A(0, 1, 0);
    asm volatile("s_waitcnt vmcnt(4)" ::: "memory");
    __builtin_amdgcn_s_barrier();

    for (int t = 0; t < NT; ++t) {
        const int d  = t & 1;
        const int e2 = d ^ 1;
        const bool pf = (t + 1) < NT;
        // ---- ph0: Q(0,0). A0(t),B0(t) bound by previous vmcnt+barrier.
        READ_A(0, d);
        READ_B(0, d, bR0);
        if (pf) STAGE_A(t + 1, 0, e2);
        if (pf) asm volatile("s_waitcnt vmcnt(4)" ::: "memory");  // binds B1(t)
        else    asm volatile("s_waitcnt vmcnt(2)" ::: "memory");
        __builtin_amdgcn_s_barrier();
        MFMA_Q(0, 0, bR0);
        // ---- ph1: Q(0,1). B1(t) bound by ph0's vmcnt+barrier.
        READ_B(1, d, bR1);
        if (pf) STAGE_B(t + 1, 0, e2);
        if (pf) asm volatile("s_waitcnt vmcnt(4)" ::: "memory");  // binds A1(t)
        else    asm volatile("s_waitcnt vmcnt(0)" ::: "memory");
        __builtin_amdgcn_s_barrier();
        MFMA_Q(0, 1, bR1);
        // ---- ph2+3 merged: Q(1,1) then Q(1,0). A1(t) bound by ph1's barrier.
        READ_A(1, d);
        if (pf) STAGE_B(t + 1, 1, e2);
        MFMA_Q(1, 1, bR1);
        if (pf) STAGE_A(t + 1, 1, e2);
        if (pf) asm volatile("s_waitcnt vmcnt(4)" ::: "memory");  // binds A0,B0(t+1)
        __builtin_amdgcn_s_barrier();
        MFMA_Q(1, 0, bR0);
    }

    // publish mr3 (global store safe now — vmcnt games over)
    if (doMR && tid < 256 && (MODE == 1 || bx == 0)) mrout[m0 + tid] = myMR;

    // epilogue: C/D layout col = lane&15, row = (lane>>4)*4 + r  [m89-verified]
    const int lg4 = (lane >> 4) << 2;
    ushort* tile = (ushort*)(smem + 2048);   // [256][264], 528B rows
    if (MODE != 1) {
        float bsv[2][2], csv[2][2], uu[2][2], vv[2][2];
#pragma unroll
        for (int qc = 0; qc < 2; ++qc)
#pragma unroll
            for (int nf = 0; nf < 2; ++nf) {
                const int col = n0 + qc * 128 + wc2 * 32 + nf * 16 + (lane & 15);
                bsv[qc][nf] = bias[col];
                csv[qc][nf] = cvec[col];
                if (MODE == 2) { uu[qc][nf] = u_[col]; vv[qc][nf] = v_[col]; }
            }
        __syncthreads();                       // drain LDS reads; staging LDS dead
        // fused epilogue + LN pass 1 (row partials over this block's 256 cols)
#pragma unroll
        for (int qr = 0; qr < 2; ++qr)
#pragma unroll
            for (int mf = 0; mf < 4; ++mf)
#pragma unroll
                for (int r = 0; r < 4; ++r) {
                    const int rloc = qr * 128 + wr2 * 64 + mf * 16 + lg4 + r;
                    float rw = 1.f, rmw = 0.f;
                    if (MODE == 2) {
                        const float2 q = mrs[rloc];
                        rw = q.y; rmw = q.y * q.x;
                    }
                    float sum = 0.f, sq = 0.f;
#pragma unroll
                    for (int qc = 0; qc < 2; ++qc)
#pragma unroll
                        for (int nf = 0; nf < 2; ++nf) {
                            float a = acc[qr][qc][mf][nf][r];
                            float val;
                            if (MODE == 2)
                                val = fmaf(rw, a, fmaf(-rmw, uu[qc][nf],
                                          vv[qc][nf] + bsv[qc][nf]));
                            else
                                val = a + bsv[qc][nf];
                            val = fmaxf(val, 0.f) + csv[qc][nf];
                            acc[qr][qc][mf][nf][r] = val;
                            sum += val; sq += val * val;
                        }
#pragma unroll
                    for (int o = 1; o < 16; o <<= 1) {
                        sum += __shfl_xor(sum, o, 64);
                        sq  += __shfl_xor(sq,  o, 64);
                    }
                    if ((lane & 15) == 0)
                        pstats_out[(((size_t)(m0 + rloc)) << 4) + (bx << 2) + wc2] =
                            make_float2(sum, sq);
                }
        // bf16 transpose tile + coalesced store into zbuf slot
#pragma unroll
        for (int qr = 0; qr < 2; ++qr)
#pragma unroll
            for (int qc = 0; qc < 2; ++qc)
#pragma unroll
                for (int mf = 0; mf < 4; ++mf)
#pragma unroll
                    for (int nf = 0; nf < 2; ++nf)
#pragma unroll
                        for (int r = 0; r < 4; ++r) {
                            const int rloc = qr * 128 + wr2 * 64 + mf * 16 + lg4 + r;
                            const int cloc = qc * 128 + wc2 * 32 + nf * 16 + (lane & 15);
                            tile[rloc * 264 + cloc] = f2bf(acc[qr][qc][mf][nf][r]);
                        }
    } else {
        // MODE 1: raw f32 acc -> f16 tile (coalesced store below)
        __syncthreads();
#pragma unroll
        for (int qr = 0; qr < 2; ++qr)
#pragma unroll
            for (int qc = 0; qc < 2; ++qc)
#pragma unroll
                for (int mf = 0; mf < 4; ++mf)
#pragma unroll
                    for (int nf = 0; nf < 2; ++nf)
#pragma unroll
                        for (int r = 0; r < 4; ++r) {
                            const int rloc = qr * 128 + wr2 * 64 + mf * 16 + lg4 + r;
                            const int cloc = qc * 128 + wc2 * 32 + nf * 16 + (lane & 15);
                            tile[rloc * 264 + cloc] = f2h(acc[qr][qc][mf][nf][r]);
                        }
    }
    __syncthreads();
    ushort* C16 = (MODE == 1)
        ? ((ushort*)Cv + (size_t)bx * ((size_t)Bv * OUTv))
        : (ushort*)Cv;
    for (int c = tid; c < 256 * 32; c += 512) {
        const int row = c >> 5, ch = (c & 31) << 3;
        const bf16x8 v = *(const bf16x8*)&tile[row * 264 + ch];
        *(bf16x8*)&C16[(size_t)(m0 + row) * ldc + n0 + ch] = v;
    }
}

// ---------------------------------------------------------------------------
// Final: per-layer LN-folded reduce + bias + LayerNorm(256) + sigmoid.
// val[n] = sum_i r_i*(ps_i[n] - m_i*uf_i[n]) + sum_i vf_i[n] + bf[n]
// psum slices are f16. 4 rows/block, 1 wave per row, 4 cols/lane.
// ---------------------------------------------------------------------------
__global__ void ln_sig_reduce(const ushort* __restrict__ ps,   // f16 (3,B,256)
                              const float2* __restrict__ mr,   // (3,B)
                              const float* __restrict__ uf,    // (3,256)
                              const float* __restrict__ vf,    // (3,256)
                              const float* __restrict__ bf_,
                              const float* __restrict__ g,
                              const float* __restrict__ bb,
                              float* __restrict__ y) {
    const int lane = threadIdx.x & 63;
    const int row  = blockIdx.x * 4 + (threadIdx.x >> 6);
    const size_t base = (size_t)row * OUTv + lane * 4;
    const size_t SP = (size_t)Bv * OUTv;
    const float2 q0 = mr[row];
    const float2 q1 = mr[Bv + row];
    const float2 q2 = mr[2 * Bv + row];
    const ushort4 a0 = *(const ushort4*)&ps[base];
    const ushort4 a1 = *(const ushort4*)&ps[base + SP];
    const ushort4 a2 = *(const ushort4*)&ps[base + 2 * SP];
    const float4 u0 = *(const float4*)&uf[lane * 4];
    const float4 u1 = *(const float4*)&uf[256 + lane * 4];
    const float4 u2 = *(const float4*)&uf[512 + lane * 4];
    const float4 f0 = *(const float4*)&vf[lane * 4];
    const float4 f1 = *(const float4*)&vf[256 + lane * 4];
    const float4 f2 = *(const float4*)&vf[512 + lane * 4];
    const float4 bv4 = *(const float4*)&bf_[lane * 4];
    const float cst_x = f0.x + f1.x + f2.x + bv4.x;
    const float cst_y = f0.y + f1.y + f2.y + bv4.y;
    const float cst_z = f0.z + f1.z + f2.z + bv4.z;
    const float cst_w = f0.w + f1.w + f2.w + bv4.w;
    const float v0 = q0.y * (h2f(a0.x) - q0.x * u0.x) + q1.y * (h2f(a1.x) - q1.x * u1.x)
                   + q2.y * (h2f(a2.x) - q2.x * u2.x) + cst_x;
    const float v1 = q0.y * (h2f(a0.y) - q0.x * u0.y) + q1.y * (h2f(a1.y) - q1.x * u1.y)
                   + q2.y * (h2f(a2.y) - q2.x * u2.y) + cst_y;
    const float v2 = q0.y * (h2f(a0.z) - q0.x * u0.z) + q1.y * (h2f(a1.z) - q1.x * u1.z)
                   + q2.y * (h2f(a2.z) - q2.x * u2.z) + cst_z;
    const float v3 = q0.y * (h2f(a0.w) - q0.x * u0.w) + q1.y * (h2f(a1.w) - q1.x * u1.w)
                   + q2.y * (h2f(a2.w) - q2.x * u2.w) + cst_w;
    float s = v0 + v1 + v2 + v3;
#pragma unroll
    for (int o = 1; o < 64; o <<= 1) s += __shfl_xor(s, o, 64);
    const float mean = s * (1.f / OUTv);
    const float d0 = v0 - mean, d1 = v1 - mean, d2 = v2 - mean, d3 = v3 - mean;
    float q = d0 * d0 + d1 * d1 + d2 * d2 + d3 * d3;
#pragma unroll
    for (int o = 1; o < 64; o <<= 1) q += __shfl_xor(q, o, 64);
    const float r = rsqrtf(q * (1.f / OUTv) + EPS);
    const float4 gg = *(const float4*)&g[lane * 4];
    const float4 bv = *(const float4*)&bb[lane * 4];
    float4 o;
    const float t0 = d0 * r * gg.x + bv.x;
    const float t1 = d1 * r * gg.y + bv.y;
    const float t2 = d2 * r * gg.z + bv.z;
    const float t3 = d3 * r * gg.w + bv.w;
    o.x = 1.f / (1.f + expf(-t0));
    o.y = 1.f / (1.f + expf(-t1));
    o.z = 1.f / (1.f + expf(-t2));
    o.w = 1.f / (1.f + expf(-t3));
    *(float4*)&y[base] = o;
}

// ---------------------------------------------------------------------------
extern "C" void kernel_launch(void* const* d_in, const int* in_sizes, int n_in,
                              void* d_out, int out_size, void* d_ws, size_t ws_size,
                              hipStream_t stream) {
    const float* x      = (const float*)d_in[0];
    const float* W      = (const float*)d_in[1];
    const float* b      = (const float*)d_in[2];
    // d_in[3] = Wq, d_in[4] = keys : dead code (softmax row-sums are 1)
    const float* values = (const float*)d_in[5];
    const float* Wout   = (const float*)d_in[6];
    const float* ln_g   = (const float*)d_in[7];
    const float* ln_b   = (const float*)d_in[8];
    const float* Wf     = (const float*)d_in[9];
    const float* bf     = (const float*)d_in[10];
    const float* lnf_g  = (const float*)d_in[11];
    const float* lnf_b  = (const float*)d_in[12];
    float* out = (float*)d_out;

    // workspace layout (~140 MB):
    char* ws = (char*)d_ws;
    ushort* zbuf = (ushort*)ws;                                  // (B,3072) bf16 RAW h + xb
    ws += (size_t)Bv * ZLD * sizeof(ushort);                     // 100.7 MB
    ushort* psum = (ushort*)ws;                                  // (3,B,256) f16 split-K partials
    ws += (size_t)3 * Bv * OUTv * sizeof(ushort);                // 25.2 MB
    ushort* Wb = (ushort*)ws;                                    // (L,1024,1024) bf16 g-folded
    ws += (size_t)Lv * Dv * Dv * sizeof(ushort);                 // 6.3 MB
    ushort* Wfb = (ushort*)ws;                                   // (256,3072) bf16 g-folded
    ws += (size_t)OUTv * ZLD * sizeof(ushort);                   // 1.6 MB
    float* cvec = (float*)ws;                                    // (L,1024)
    ws += (size_t)Lv * Dv * sizeof(float);
    float* vmean = (float*)ws;                                   // (L,256)
    ws += (size_t)Lv * Vv * sizeof(float);
    float2* psA = (float2*)ws;                                   // (B,16) ping
    ws += (size_t)Bv * 16 * sizeof(float2);                      // 2 MB
    float2* psB = (float2*)ws;                                   // (B,16) pong
    ws += (size_t)Bv * 16 * sizeof(float2);                      // 2 MB
    float2* mr3 = (float2*)ws;                                   // (3,B)
    ws += (size_t)3 * Bv * sizeof(float2);                       // 384 KB
    float* ub = (float*)ws; ws += 2 * Dv * sizeof(float);        // (2,1024)
    float* vb = (float*)ws; ws += 2 * Dv * sizeof(float);
    float* uf = (float*)ws; ws += 3 * OUTv * sizeof(float);      // (3,256)
    float* vf = (float*)ws; ws += 3 * OUTv * sizeof(float);

    // prep (single-read fused weight converts + fold vectors)
    wprep<<<Lv * Dv, 256, 0, stream>>>(W, ln_g, ln_b, Wb, ub, vb);
    wfprep<<<3 * OUTv, 256, 0, stream>>>(Wf, ln_g, ln_b, Wfb, uf, vf);
    conv_x<<<Bv * 128 / 256, 256, 0, stream>>>(x, zbuf);
    vmean_kernel<<<Lv, 256, 0, stream>>>(values, vmean);
    cvec_kernel<<<Lv * Dv / 8, 512, 0, stream>>>(vmean, Wout, cvec);

    // layer 0: A = xb (cols 2048:3072) -> raw h0 + pstats into psA
    gemm256<0><<<dim3(256), 512, 0, stream>>>(
        zbuf + 2048, ZLD, Wb, Dv,
        b, cvec, nullptr, nullptr, nullptr, nullptr,
        (void*)(zbuf + 0), ZLD, /*NT=*/16, 0, psA);

    // layer 1: fused mr(layer0) from psA; writes pstats(layer1) -> psB
    gemm256<2><<<dim3(256), 512, 0, stream>>>(
        zbuf, ZLD, Wb + (size_t)Dv * Dv, Dv,
        b + Dv, cvec + Dv, ub, vb, psA, mr3,
        (void*)(zbuf + Dv), ZLD, /*NT=*/16, 0, psB);

    // layer 2: fused mr(layer1) from psB; writes pstats(layer2) -> psA
    gemm256<2><<<dim3(256), 512, 0, stream>>>(
        zbuf + Dv, ZLD, Wb + (size_t)2 * Dv * Dv, Dv,
        b + 2 * Dv, cvec + 2 * Dv, ub + Dv, vb + Dv, psB, mr3 + Bv,
        (void*)(zbuf + 2 * Dv), ZLD, /*NT=*/16, 0, psA);

    // final GEMM: split-K by layer (3 x K=1024), 192 blocks, f16 partials;
    // bx==2 blocks also compute+publish mr3(layer2) from psA.
    gemm256<1><<<dim3(192), 512, 0, stream>>>(
        zbuf, ZLD, Wfb, ZLD, nullptr, nullptr, nullptr, nullptr,
        psA, mr3 + 2 * Bv,
        (void*)psum, OUTv, /*NT=*/16, /*ksplit=*/1024, nullptr);

    ln_sig_reduce<<<Bv / 4, 256, 0, stream>>>(psum, mr3, uf, vf, bf,
                                              lnf_g, lnf_b, out);
}